// Round 11
// baseline (584.005 us; speedup 1.0000x reference)
//
#include <hip/hip_runtime.h>

// VQ-VAE VectorQuantizer2: z [4,8,64,64] f32, emb [16384,8] f32
// outputs: z_q [4,8,64,64] f32 | loss [1] f32 | idx [16384] written as f32
//
// R11 architecture: SINGLE fused MFMA filter kernel (per-split threshold)
//                   + inline exact compare via atomicMin(u64).
//  - d_k = fl(Zn - fl(2*dot_k)) MONOTONE in dot_k. Any k that can win the
//    argmin satisfies dot_k >= dot* - q/2 >= split_max_exact - q/2, so
//    dot~_k >= split_max~ - (q/2 + 2*delta). W = Zn*1.5e-7 + 1e-7 covers
//    q/2 + 2*delta with margin (R9/R10-proven) -> per-split thr = max~_s - W
//    collects a guaranteed superset (slightly larger than global-thr's).
//  - bf16 two-term split packed into K=32: A=[z_hi,z_lo,z_hi,z_lo],
//    B=[e_hi,e_lo,e_lo,e_hi] -> mfma_f32_16x16x32_bf16 = z.e to ~2e-9.
//  - Pass 1 (LDS staged once): per-(row,split) max, per-lane pk_max only,
//    ONE cross-lane reduce. Pass 2: same staged codes, packed hit-detect,
//    leaf hit -> EXACT reference f32 chain (z from global, rare) ->
//    fire-and-forget atomicMin(key[row], monotone(dd)<<32|k) == first-index
//    argmin (ties broken by smaller k in low bits).
//  - 17 KB LDS -> 8 blocks/CU (R10's 42 KB capped occupancy at 18.6%).

typedef short bf16x8 __attribute__((ext_vector_type(8)));
typedef float f32x4  __attribute__((ext_vector_type(4)));
typedef float f32x2  __attribute__((ext_vector_type(2)));

#define N_ROW 16384
#define N_E   16384
#define NSPL  32
#define SPLIT (N_E / NSPL)     // 512 codes per split
#define TILES (SPLIT / 16)     // 32
#define FIN_BLOCKS (N_ROW / 256)

static __device__ __forceinline__ unsigned short bf16_rne(float x) {
    unsigned u = __float_as_uint(x);
    unsigned r = (u >> 16) & 1u;
    return (unsigned short)((u + 0x7FFFu + r) >> 16);
}

// ---------------- prep: one-time bf16 hi/lo splits + Zn ----------------
__global__ __launch_bounds__(256) void vq_prep(const float* __restrict__ z,
                                               const float* __restrict__ emb,
                                               unsigned short* __restrict__ pz,
                                               unsigned short* __restrict__ pe_hi,
                                               unsigned short* __restrict__ pe_lo,
                                               float* __restrict__ Zn_arr) {
    const int t = blockIdx.x * 256 + threadIdx.x;       // 0..32767
    if (t < N_ROW) {
        const int b = t >> 12, hw = t & 4095;
        const float* zp = z + (size_t)b * 32768 + hw;
        float v[8];
#pragma unroll
        for (int c = 0; c < 8; ++c) v[c] = zp[c * 4096];
        float Zn;
        {   // sequential f32 sum of squares, NO fma contraction (numerics contract)
#pragma clang fp contract(off)
            Zn = v[0] * v[0];
#pragma unroll
            for (int c = 1; c < 8; ++c) { float q = v[c] * v[c]; Zn = Zn + q; }
        }
        unsigned hb[8], lb[8];
#pragma unroll
        for (int c = 0; c < 8; ++c) {
            hb[c] = bf16_rne(v[c]);
            float hf = __uint_as_float(hb[c] << 16);
            lb[c] = bf16_rne(v[c] - hf);                // residual Sterbenz-exact
        }
        uint4 uh, ul;
        uh.x = hb[0] | (hb[1] << 16); uh.y = hb[2] | (hb[3] << 16);
        uh.z = hb[4] | (hb[5] << 16); uh.w = hb[6] | (hb[7] << 16);
        ul.x = lb[0] | (lb[1] << 16); ul.y = lb[2] | (lb[3] << 16);
        ul.z = lb[4] | (lb[5] << 16); ul.w = lb[6] | (lb[7] << 16);
        ((uint4*)pz)[(size_t)t * 2]     = uh;           // [hi octet | lo octet]
        ((uint4*)pz)[(size_t)t * 2 + 1] = ul;
        Zn_arr[t] = Zn;
    } else {
        const int k = t - N_ROW;                        // code index
        const float* e = emb + (size_t)k * 8;
        float v[8];
#pragma unroll
        for (int c = 0; c < 8; ++c) v[c] = e[c];
        unsigned hb[8], lb[8];
#pragma unroll
        for (int c = 0; c < 8; ++c) {
            hb[c] = bf16_rne(v[c]);
            float hf = __uint_as_float(hb[c] << 16);
            lb[c] = bf16_rne(v[c] - hf);
        }
        uint4 uh, ul;
        uh.x = hb[0] | (hb[1] << 16); uh.y = hb[2] | (hb[3] << 16);
        uh.z = hb[4] | (hb[5] << 16); uh.w = hb[6] | (hb[7] << 16);
        ul.x = lb[0] | (lb[1] << 16); ul.y = lb[2] | (lb[3] << 16);
        ul.z = lb[4] | (lb[5] << 16); ul.w = lb[6] | (lb[7] << 16);
        ((uint4*)pe_hi)[k] = uh;
        ((uint4*)pe_lo)[k] = ul;
    }
}

// ---------------- fused scan: in-block max -> threshold -> collect --------
__global__ __launch_bounds__(256, 4) void vq_scan(const float* __restrict__ z,
                                                  const float* __restrict__ emb,
                                                  const unsigned short* __restrict__ pe_hi,
                                                  const unsigned short* __restrict__ pe_lo,
                                                  const unsigned short* __restrict__ pz,
                                                  const float* __restrict__ Zn_arr,
                                                  unsigned long long* __restrict__ key) {
    __shared__ __align__(16) unsigned short se_hi[SPLIT * 8];   // 8 KB
    __shared__ __align__(16) unsigned short se_lo[SPLIT * 8];   // 8 KB
    __shared__ float sZn[256];                                  // 1 KB
    const int tid = threadIdx.x, wid = tid >> 6, lane = tid & 63;
    const int rowbase = (int)(blockIdx.x >> 5) * 256;
    const int split = blockIdx.x & 31;
    const int col = lane & 15, g = lane >> 4;
    const unsigned short* seB = (g == 1 || g == 2) ? se_lo : se_hi;  // B: hi,lo,lo,hi

    bf16x8 afrag[4];                                    // A: [hi,lo,hi,lo] -> (g&1)
#pragma unroll
    for (int a = 0; a < 4; ++a)
        afrag[a] = *(const bf16x8*)(pz + (size_t)(rowbase + wid * 64 + a * 16 + col) * 16 + (g & 1) * 8);

    {   // stage 512 codes x 16 B per array (pure copies) + Zn rows
        const uint4* gh = (const uint4*)(pe_hi + (size_t)split * SPLIT * 8);
        const uint4* gl = (const uint4*)(pe_lo + (size_t)split * SPLIT * 8);
        ((uint4*)se_hi)[tid]       = gh[tid];
        ((uint4*)se_hi)[tid + 256] = gh[tid + 256];
        ((uint4*)se_lo)[tid]       = gl[tid];
        ((uint4*)se_lo)[tid + 256] = gl[tid + 256];
        sZn[tid] = Zn_arr[rowbase + tid];
    }
    __syncthreads();

    const f32x4 zero4 = {0.f, 0.f, 0.f, 0.f};

    // ---- pass 1: per-lane max (packed), staged LDS only ----
    f32x2 rmax2[8];
#pragma unroll
    for (int i = 0; i < 8; ++i) rmax2[i] = (f32x2){-3.4e38f, -3.4e38f};
#pragma unroll 2
    for (int t = 0; t < TILES; ++t) {
        const bf16x8 bfrag = *(const bf16x8*)(seB + (size_t)(t * 16 + col) * 8);
        f32x4 cc[4];
        cc[0] = __builtin_amdgcn_mfma_f32_16x16x32_bf16(afrag[0], bfrag, zero4, 0, 0, 0);
        cc[1] = __builtin_amdgcn_mfma_f32_16x16x32_bf16(afrag[1], bfrag, zero4, 0, 0, 0);
        cc[2] = __builtin_amdgcn_mfma_f32_16x16x32_bf16(afrag[2], bfrag, zero4, 0, 0, 0);
        cc[3] = __builtin_amdgcn_mfma_f32_16x16x32_bf16(afrag[3], bfrag, zero4, 0, 0, 0);
#pragma unroll
        for (int a = 0; a < 4; ++a) {                   // v_pk_max_f32
            f32x2 lo2 = __builtin_shufflevector(cc[a], cc[a], 0, 1);
            f32x2 hi2 = __builtin_shufflevector(cc[a], cc[a], 2, 3);
            rmax2[a * 2]     = __builtin_elementwise_max(rmax2[a * 2], lo2);
            rmax2[a * 2 + 1] = __builtin_elementwise_max(rmax2[a * 2 + 1], hi2);
        }
    }

    // ---- one cross-lane reduce -> per-row threshold (in registers) ----
    f32x2 thr2[4][2];
#pragma unroll
    for (int a = 0; a < 4; ++a)
#pragma unroll
        for (int r = 0; r < 4; ++r) {
            float m = rmax2[a * 2 + (r >> 1)][r & 1];
            m = fmaxf(m, __shfl_xor(m, 1));
            m = fmaxf(m, __shfl_xor(m, 2));
            m = fmaxf(m, __shfl_xor(m, 4));
            m = fmaxf(m, __shfl_xor(m, 8));
            // W = Zn*1.5e-7 + 1e-7 >= q/2 (ulp, binade-crossing) + 2*delta
            const float Znr = sZn[wid * 64 + a * 16 + g * 4 + r];
            thr2[a][r >> 1][r & 1] = m - __builtin_fmaf(Znr, 1.5e-7f, 1e-7f);
        }

    // ---- pass 2: re-sweep same staged codes, collect via atomicMin ----
#pragma unroll 2
    for (int t = 0; t < TILES; ++t) {
        const bf16x8 bfrag = *(const bf16x8*)(seB + (size_t)(t * 16 + col) * 8);
        f32x4 cc[4];
        cc[0] = __builtin_amdgcn_mfma_f32_16x16x32_bf16(afrag[0], bfrag, zero4, 0, 0, 0);
        cc[1] = __builtin_amdgcn_mfma_f32_16x16x32_bf16(afrag[1], bfrag, zero4, 0, 0, 0);
        cc[2] = __builtin_amdgcn_mfma_f32_16x16x32_bf16(afrag[2], bfrag, zero4, 0, 0, 0);
        cc[3] = __builtin_amdgcn_mfma_f32_16x16x32_bf16(afrag[3], bfrag, zero4, 0, 0, 0);

        f32x2 d[4][2], mx;
#pragma unroll
        for (int a = 0; a < 4; ++a) {
            f32x2 lo2 = __builtin_shufflevector(cc[a], cc[a], 0, 1);
            f32x2 hi2 = __builtin_shufflevector(cc[a], cc[a], 2, 3);
            d[a][0] = lo2 - thr2[a][0];
            d[a][1] = hi2 - thr2[a][1];
            f32x2 m2 = __builtin_elementwise_max(d[a][0], d[a][1]);
            mx = (a == 0) ? m2 : __builtin_elementwise_max(mx, m2);
        }
        if (__any(fmaxf(mx.x, mx.y) >= 0.f)) {
            const int kcode = split * SPLIT + t * 16 + col;
#pragma unroll
            for (int a = 0; a < 4; ++a) {
                f32x2 am2 = __builtin_elementwise_max(d[a][0], d[a][1]);
                if (__any(fmaxf(am2.x, am2.y) >= 0.f)) {
#pragma unroll
                    for (int r = 0; r < 4; ++r) {
                        const float dv = d[a][r >> 1][r & 1];
                        if (__any(dv >= 0.f)) {
                            if (dv >= 0.f) {            // leaf divergence only (rare)
                                const int lrow = wid * 64 + a * 16 + g * 4 + r;
                                const int row = rowbase + lrow;
                                const float* zr = z + (size_t)(row >> 12) * 32768 + (row & 4095);
                                const float* e  = emb + (size_t)kcode * 8;
                                // EXACT chain (identical ops to reference)
                                float dot = zr[0] * e[0];
#pragma unroll
                                for (int c = 1; c < 8; ++c)
                                    dot = __builtin_fmaf(zr[(size_t)c * 4096], e[c], dot);
                                const float dd = __builtin_fmaf(-2.f, dot, sZn[lrow]);
                                unsigned u = __float_as_uint(dd);
                                unsigned mm = (u & 0x80000000u) ? ~u : (u | 0x80000000u);
                                const unsigned long long kk =
                                    ((unsigned long long)mm << 32) | (unsigned)kcode;
                                atomicMin(&key[(size_t)row], kk);   // fire-and-forget
                            }
                        }
                    }
                }
            }
        }
    }
}

// ---------------- finalize: gather winner, outputs + loss ----------------
__global__ __launch_bounds__(256) void vq_fin(const float* __restrict__ z,
                                              const float* __restrict__ emb,
                                              const unsigned long long* __restrict__ key,
                                              float* __restrict__ out_zq,
                                              float* __restrict__ out_idx,
                                              double* __restrict__ acc,
                                              unsigned* __restrict__ done,
                                              float* __restrict__ out_loss) {
    __shared__ float red[4];
    const int row = blockIdx.x * 256 + threadIdx.x;
    const int b = row >> 12, hw = row & 4095;
    const int kstar = (int)(unsigned)(key[row] & 0xFFFFFFFFull);
    out_idx[row] = (float)kstar;
    const float* e = emb + (size_t)kstar * 8;
    float s = 0.f;
#pragma unroll
    for (int c = 0; c < 8; ++c) {
        const size_t zoff = (size_t)b * 32768 + (size_t)c * 4096 + hw;
        const float ev = e[c];
        const float df = ev - z[zoff];
        out_zq[zoff] = ev;
        s = __builtin_fmaf(df, df, s);
    }
#pragma unroll
    for (int off = 32; off > 0; off >>= 1) s += __shfl_down(s, off, 64);
    if ((threadIdx.x & 63) == 0) red[threadIdx.x >> 6] = s;
    __syncthreads();
    if (threadIdx.x == 0) {
        double t = (double)red[0] + (double)red[1] + (double)red[2] + (double)red[3];
        atomicAdd(acc, t);
        __threadfence();
        unsigned old = atomicAdd(done, 1u);
        if (old == FIN_BLOCKS - 1) {
            double total = atomicAdd(acc, 0.0);
            float mf = (float)(total / (double)(N_ROW * 8));
            out_loss[0] = mf + 0.25f * mf;   // fwd values of the two terms are equal
        }
    }
}

extern "C" void kernel_launch(void* const* d_in, const int* in_sizes, int n_in,
                              void* d_out, int out_size, void* d_ws, size_t ws_size,
                              hipStream_t stream) {
    const float* z   = (const float*)d_in[0];
    const float* emb = (const float*)d_in[1];

    float* out      = (float*)d_out;
    float* out_zq   = out;               // 131072
    float* out_loss = out + 131072;      // 1
    float* out_idx  = out + 131073;      // 16384

    // ws layout (~1.2 MB; R2 proved ws >= 8.4 MB):
    char* w = (char*)d_ws;
    double*             acc   = (double*)w;
    unsigned*           done  = (unsigned*)(w + 8);      w += 64;
    unsigned long long* key   = (unsigned long long*)w;  w += (size_t)N_ROW * 8;
    float*              Zn    = (float*)w;               w += (size_t)N_ROW * 4;
    unsigned short*     pz    = (unsigned short*)w;      w += (size_t)N_ROW * 32;
    unsigned short*     pe_hi = (unsigned short*)w;      w += (size_t)N_E * 16;
    unsigned short*     pe_lo = (unsigned short*)w;      w += (size_t)N_E * 16;

    hipMemsetAsync(d_ws, 0, 64, stream);                       // acc + done
    hipMemsetAsync(key, 0xFF, (size_t)N_ROW * 8, stream);      // key = ~0ull
    vq_prep <<<dim3(128), dim3(256), 0, stream>>>(z, emb, pz, pe_hi, pe_lo, Zn);
    vq_scan <<<dim3((N_ROW / 256) * NSPL), dim3(256), 0, stream>>>(z, emb, pe_hi, pe_lo, pz, Zn, key);
    vq_fin  <<<dim3(FIN_BLOCKS), dim3(256), 0, stream>>>(z, emb, key, out_zq, out_idx, acc, done, out_loss);
}

// Round 12
// 304.693 us; speedup vs baseline: 1.9167x; 1.9167x over previous
//
#include <hip/hip_runtime.h>

// VQ-VAE VectorQuantizer2: z [4,8,64,64] f32, emb [16384,8] f32
// outputs: z_q [4,8,64,64] f32 | loss [1] f32 | idx [16384] written as f32
//
// R12 architecture (global-threshold filter, R10-proven dataflow, lean kernels):
//  prep: z bf16 hi/lo split + Zn + e bf16 HI split + key/ctr init
//  maxk: per-(row,split) max of dot~ = z . e_hi   [A=[z_hi,z_lo,z_hi,z_lo],
//        B octets [e_hi,0,0,e_hi] -> MFMA = (z_hi+z_lo).e_hi = z.e_hi exactly]
//  thr : thr[row] = max_s - W,  W = 1.5e-7*Zn + 6.8e-7*sqrt(Zn) + 2e-7
//        >= q/2 (d-ulp incl binade) + 2*delta' (delta' = |z.e_lo| <= 3.4e-7*sqrt(Zn))
//  coll: re-sweep; hit -> append (row<<14|code) via atomicAdd (3-instr leaf;
//        R11's fat leaf caused an 830B/thread scratch spill = 8x regression)
//  fin2: exact reference f32 chain on each pair -> atomicMin(key[row],
//        monotone(dd)<<32|k)  == lexicographic (dd,k) min == first-index argmin
//  fin : gather winner, write z_q/idx, reduce loss; full-scan fallback if
//        pairs overflowed (never in practice).

typedef short bf16x8 __attribute__((ext_vector_type(8)));
typedef float f32x4  __attribute__((ext_vector_type(4)));
typedef float f32x2  __attribute__((ext_vector_type(2)));

#define N_ROW 16384
#define N_E   16384
#define NSPL  32
#define SPLIT (N_E / NSPL)     // 512 codes per split
#define TILES (SPLIT / 16)     // 32
#define PCAP  262144           // pair buffer capacity (1 MB)
#define FIN_BLOCKS (N_ROW / 256)

static __device__ __forceinline__ unsigned short bf16_rne(float x) {
    unsigned u = __float_as_uint(x);
    unsigned r = (u >> 16) & 1u;
    return (unsigned short)((u + 0x7FFFu + r) >> 16);
}

// ---------------- prep: one-time conversions + init ----------------
__global__ __launch_bounds__(256) void vq_prep(const float* __restrict__ z,
                                               const float* __restrict__ emb,
                                               unsigned short* __restrict__ pz,
                                               unsigned short* __restrict__ pe_hi,
                                               float* __restrict__ Zn_arr,
                                               unsigned long long* __restrict__ key,
                                               double* __restrict__ acc,
                                               unsigned* __restrict__ done,
                                               unsigned* __restrict__ gcnt) {
    const int t = blockIdx.x * 256 + threadIdx.x;       // 0..32767
    if (t < N_ROW) {
        const int b = t >> 12, hw = t & 4095;
        const float* zp = z + (size_t)b * 32768 + hw;
        float v[8];
#pragma unroll
        for (int c = 0; c < 8; ++c) v[c] = zp[c * 4096];
        float Zn;
        {   // sequential f32 sum of squares, NO fma contraction (numerics contract)
#pragma clang fp contract(off)
            Zn = v[0] * v[0];
#pragma unroll
            for (int c = 1; c < 8; ++c) { float q = v[c] * v[c]; Zn = Zn + q; }
        }
        unsigned hb[8], lb[8];
#pragma unroll
        for (int c = 0; c < 8; ++c) {
            hb[c] = bf16_rne(v[c]);
            float hf = __uint_as_float(hb[c] << 16);
            lb[c] = bf16_rne(v[c] - hf);                // residual Sterbenz-exact
        }
        uint4 uh, ul;
        uh.x = hb[0] | (hb[1] << 16); uh.y = hb[2] | (hb[3] << 16);
        uh.z = hb[4] | (hb[5] << 16); uh.w = hb[6] | (hb[7] << 16);
        ul.x = lb[0] | (lb[1] << 16); ul.y = lb[2] | (lb[3] << 16);
        ul.z = lb[4] | (lb[5] << 16); ul.w = lb[6] | (lb[7] << 16);
        ((uint4*)pz)[(size_t)t * 2]     = uh;           // [hi octet | lo octet]
        ((uint4*)pz)[(size_t)t * 2 + 1] = ul;
        Zn_arr[t] = Zn;
        key[t] = ~0ull;
        if (t == 0) { *acc = 0.0; *done = 0u; *gcnt = 0u; }
    } else {
        const int k = t - N_ROW;                        // code index: HI part only
        const float* e = emb + (size_t)k * 8;
        unsigned hb[8];
#pragma unroll
        for (int c = 0; c < 8; ++c) hb[c] = bf16_rne(e[c]);
        uint4 uh;
        uh.x = hb[0] | (hb[1] << 16); uh.y = hb[2] | (hb[3] << 16);
        uh.z = hb[4] | (hb[5] << 16); uh.w = hb[6] | (hb[7] << 16);
        ((uint4*)pe_hi)[k] = uh;
    }
}

// ---------------- pass 1: per-(row,split) max of dot~, transposed store ----
__global__ __launch_bounds__(256, 4) void vq_maxk(const unsigned short* __restrict__ pe_hi,
                                                  const unsigned short* __restrict__ pz,
                                                  float* __restrict__ maxs) {
    __shared__ __align__(16) unsigned short se_hi[SPLIT * 8];   // 8 KB
    const int tid = threadIdx.x, wid = tid >> 6, lane = tid & 63;
    const int rowbase = (int)(blockIdx.x >> 5) * 256;
    const int split = blockIdx.x & 31;
    const int col = lane & 15, g = lane >> 4;
    const bool mid = (g == 1 || g == 2);                // B octets [hi,0,0,hi]

    bf16x8 afrag[4];                                    // A octets [hi,lo,hi,lo] -> (g&1)
#pragma unroll
    for (int a = 0; a < 4; ++a)
        afrag[a] = *(const bf16x8*)(pz + (size_t)(rowbase + wid * 64 + a * 16 + col) * 16 + (g & 1) * 8);

    {   // stage 512 codes x 16 B (pure copies)
        const uint4* gh = (const uint4*)(pe_hi + (size_t)split * SPLIT * 8);
        ((uint4*)se_hi)[tid]       = gh[tid];
        ((uint4*)se_hi)[tid + 256] = gh[tid + 256];
    }
    __syncthreads();

    const f32x4 zero4 = {0.f, 0.f, 0.f, 0.f};
    const bf16x8 zfrag = {0, 0, 0, 0, 0, 0, 0, 0};
    f32x2 rmax2[8];
#pragma unroll
    for (int i = 0; i < 8; ++i) rmax2[i] = (f32x2){-3.4e38f, -3.4e38f};

#pragma unroll 2
    for (int t = 0; t < TILES; ++t) {
        const bf16x8 bfrag = mid ? zfrag
                                 : *(const bf16x8*)(se_hi + (size_t)(t * 16 + col) * 8);
        f32x4 cc[4];
        cc[0] = __builtin_amdgcn_mfma_f32_16x16x32_bf16(afrag[0], bfrag, zero4, 0, 0, 0);
        cc[1] = __builtin_amdgcn_mfma_f32_16x16x32_bf16(afrag[1], bfrag, zero4, 0, 0, 0);
        cc[2] = __builtin_amdgcn_mfma_f32_16x16x32_bf16(afrag[2], bfrag, zero4, 0, 0, 0);
        cc[3] = __builtin_amdgcn_mfma_f32_16x16x32_bf16(afrag[3], bfrag, zero4, 0, 0, 0);
#pragma unroll
        for (int a = 0; a < 4; ++a) {                   // v_pk_max_f32
            f32x2 lo2 = __builtin_shufflevector(cc[a], cc[a], 0, 1);
            f32x2 hi2 = __builtin_shufflevector(cc[a], cc[a], 2, 3);
            rmax2[a * 2]     = __builtin_elementwise_max(rmax2[a * 2], lo2);
            rmax2[a * 2 + 1] = __builtin_elementwise_max(rmax2[a * 2 + 1], hi2);
        }
    }
#pragma unroll
    for (int a = 0; a < 4; ++a)
#pragma unroll
        for (int r = 0; r < 4; ++r) {
            float m = rmax2[a * 2 + (r >> 1)][r & 1];
            m = fmaxf(m, __shfl_xor(m, 1));
            m = fmaxf(m, __shfl_xor(m, 2));
            m = fmaxf(m, __shfl_xor(m, 4));
            m = fmaxf(m, __shfl_xor(m, 8));
            if (col == 0)   // TRANSPOSED: [split][row]
                maxs[(size_t)split * N_ROW + (rowbase + wid * 64 + a * 16 + g * 4 + r)] = m;
        }
}

// ---------------- tiny: global threshold per row ----------------
__global__ __launch_bounds__(256) void vq_thr(const float* __restrict__ maxs,
                                              const float* __restrict__ Zn_arr,
                                              float* __restrict__ thr) {
    const int row = blockIdx.x * 256 + threadIdx.x;
    float m = -3.4e38f;
#pragma unroll
    for (int s = 0; s < NSPL; ++s) m = fmaxf(m, maxs[(size_t)s * N_ROW + row]);
    const float Zn = Zn_arr[row];
    // W >= q/2 (ulp of d, binade-crossing) + 2*delta', delta' <= 3.4e-7*sqrt(Zn)
    const float W = __builtin_fmaf(Zn, 1.5e-7f, __builtin_fmaf(__builtin_sqrtf(Zn), 6.8e-7f, 2e-7f));
    thr[row] = m - W;
}

// ---------------- pass 2: sweep + 3-instr append leaf ----------------
__global__ __launch_bounds__(256, 4) void vq_coll(const unsigned short* __restrict__ pe_hi,
                                                  const unsigned short* __restrict__ pz,
                                                  const float* __restrict__ thr_arr,
                                                  unsigned* __restrict__ pairs,
                                                  unsigned* __restrict__ gcnt) {
    __shared__ __align__(16) unsigned short se_hi[SPLIT * 8];   // 8 KB
    __shared__ float sthr[256];                                 // 1 KB
    const int tid = threadIdx.x, wid = tid >> 6, lane = tid & 63;
    const int rowbase = (int)(blockIdx.x >> 5) * 256;
    const int split = blockIdx.x & 31;
    const int col = lane & 15, g = lane >> 4;
    const bool mid = (g == 1 || g == 2);

    bf16x8 afrag[4];
#pragma unroll
    for (int a = 0; a < 4; ++a)
        afrag[a] = *(const bf16x8*)(pz + (size_t)(rowbase + wid * 64 + a * 16 + col) * 16 + (g & 1) * 8);

    {
        const uint4* gh = (const uint4*)(pe_hi + (size_t)split * SPLIT * 8);
        ((uint4*)se_hi)[tid]       = gh[tid];
        ((uint4*)se_hi)[tid + 256] = gh[tid + 256];
        sthr[tid] = thr_arr[rowbase + tid];
    }
    __syncthreads();

    f32x2 thr2[4][2];
#pragma unroll
    for (int a = 0; a < 4; ++a) {
        const int lr = wid * 64 + a * 16 + g * 4;
        thr2[a][0] = (f32x2){sthr[lr],     sthr[lr + 1]};
        thr2[a][1] = (f32x2){sthr[lr + 2], sthr[lr + 3]};
    }

    const f32x4 zero4 = {0.f, 0.f, 0.f, 0.f};
    const bf16x8 zfrag = {0, 0, 0, 0, 0, 0, 0, 0};
#pragma unroll 2
    for (int t = 0; t < TILES; ++t) {
        const bf16x8 bfrag = mid ? zfrag
                                 : *(const bf16x8*)(se_hi + (size_t)(t * 16 + col) * 8);
        f32x4 cc[4];
        cc[0] = __builtin_amdgcn_mfma_f32_16x16x32_bf16(afrag[0], bfrag, zero4, 0, 0, 0);
        cc[1] = __builtin_amdgcn_mfma_f32_16x16x32_bf16(afrag[1], bfrag, zero4, 0, 0, 0);
        cc[2] = __builtin_amdgcn_mfma_f32_16x16x32_bf16(afrag[2], bfrag, zero4, 0, 0, 0);
        cc[3] = __builtin_amdgcn_mfma_f32_16x16x32_bf16(afrag[3], bfrag, zero4, 0, 0, 0);

        f32x2 d[4][2], mx;
#pragma unroll
        for (int a = 0; a < 4; ++a) {
            f32x2 lo2 = __builtin_shufflevector(cc[a], cc[a], 0, 1);
            f32x2 hi2 = __builtin_shufflevector(cc[a], cc[a], 2, 3);
            d[a][0] = lo2 - thr2[a][0];
            d[a][1] = hi2 - thr2[a][1];
            f32x2 m2 = __builtin_elementwise_max(d[a][0], d[a][1]);
            mx = (a == 0) ? m2 : __builtin_elementwise_max(mx, m2);
        }
        if (__any(fmaxf(mx.x, mx.y) >= 0.f)) {
            const int kcode = split * SPLIT + t * 16 + col;
#pragma unroll
            for (int a = 0; a < 4; ++a)
#pragma unroll
                for (int r = 0; r < 4; ++r) {
                    const float dv = d[a][r >> 1][r & 1];
                    if (__any(dv >= 0.f)) {
                        if (dv >= 0.f) {                // 3-instr leaf: no spill risk
                            const unsigned row = rowbase + wid * 64 + a * 16 + g * 4 + r;
                            const unsigned p = atomicAdd(gcnt, 1u);
                            if (p < PCAP) pairs[p] = (row << 14) | (unsigned)kcode;
                        }
                    }
                }
        }
    }
}

// ---------------- fin2: exact chain per pair -> atomicMin key ----------------
__global__ __launch_bounds__(256) void vq_fin2(const float* __restrict__ z,
                                               const float* __restrict__ emb,
                                               const unsigned* __restrict__ pairs,
                                               const unsigned* __restrict__ gcnt,
                                               const float* __restrict__ Zn_arr,
                                               unsigned long long* __restrict__ key) {
    const unsigned n = min(*gcnt, (unsigned)PCAP);
    for (unsigned i = blockIdx.x * 256 + threadIdx.x; i < n; i += 256 * 256) {
        const unsigned p = pairs[i];
        const unsigned row = p >> 14, k = p & 16383u;
        const float* zr = z + (size_t)(row >> 12) * 32768 + (row & 4095);
        const float* e  = emb + (size_t)k * 8;
        const float Zn = Zn_arr[row];
        // EXACT chain (identical ops to reference)
        float dot = zr[0] * e[0];
#pragma unroll
        for (int c = 1; c < 8; ++c) dot = __builtin_fmaf(zr[(size_t)c * 4096], e[c], dot);
        const float dd = __builtin_fmaf(-2.f, dot, Zn);
        unsigned u = __float_as_uint(dd);
        unsigned mm = (u & 0x80000000u) ? ~u : (u | 0x80000000u);   // monotone total order
        atomicMin(&key[row], ((unsigned long long)mm << 32) | k);
    }
}

// ---------------- finalize: gather winner, outputs + loss ----------------
__global__ __launch_bounds__(256) void vq_fin(const float* __restrict__ z,
                                              const float* __restrict__ emb,
                                              const unsigned long long* __restrict__ key,
                                              const unsigned* __restrict__ gcnt,
                                              const float* __restrict__ Zn_arr,
                                              float* __restrict__ out_zq,
                                              float* __restrict__ out_idx,
                                              double* __restrict__ acc,
                                              unsigned* __restrict__ done,
                                              float* __restrict__ out_loss) {
    __shared__ float red[4];
    const int row = blockIdx.x * 256 + threadIdx.x;
    const int b = row >> 12, hw = row & 4095;
    int kstar;
    if (*gcnt <= (unsigned)PCAP) {
        kstar = (int)(unsigned)(key[row] & 0xFFFFFFFFull);
    } else {
        // overflow fallback (never in practice): exact full scan, first-index argmin
        const float* zr = z + (size_t)b * 32768 + hw;
        float zv[8];
#pragma unroll
        for (int c = 0; c < 8; ++c) zv[c] = zr[(size_t)c * 4096];
        const float Zn = Zn_arr[row];
        unsigned long long best = ~0ull;
        for (int k = 0; k < N_E; ++k) {
            const float* e = emb + (size_t)k * 8;
            float dot = zv[0] * e[0];
#pragma unroll
            for (int c = 1; c < 8; ++c) dot = __builtin_fmaf(zv[c], e[c], dot);
            const float dd = __builtin_fmaf(-2.f, dot, Zn);
            unsigned u = __float_as_uint(dd);
            unsigned mm = (u & 0x80000000u) ? ~u : (u | 0x80000000u);
            unsigned long long kk = ((unsigned long long)mm << 32) | (unsigned)k;
            if (kk < best) best = kk;
        }
        kstar = (int)(unsigned)(best & 0xFFFFFFFFull);
    }
    out_idx[row] = (float)kstar;
    const float* e = emb + (size_t)kstar * 8;
    float s = 0.f;
#pragma unroll
    for (int c = 0; c < 8; ++c) {
        const size_t zoff = (size_t)b * 32768 + (size_t)c * 4096 + hw;
        const float ev = e[c];
        const float df = ev - z[zoff];
        out_zq[zoff] = ev;
        s = __builtin_fmaf(df, df, s);
    }
#pragma unroll
    for (int off = 32; off > 0; off >>= 1) s += __shfl_down(s, off, 64);
    if ((threadIdx.x & 63) == 0) red[threadIdx.x >> 6] = s;
    __syncthreads();
    if (threadIdx.x == 0) {
        double t = (double)red[0] + (double)red[1] + (double)red[2] + (double)red[3];
        atomicAdd(acc, t);
        __threadfence();
        unsigned old = atomicAdd(done, 1u);
        if (old == FIN_BLOCKS - 1) {
            double total = atomicAdd(acc, 0.0);
            float mf = (float)(total / (double)(N_ROW * 8));
            out_loss[0] = mf + 0.25f * mf;   // fwd values of the two terms are equal
        }
    }
}

extern "C" void kernel_launch(void* const* d_in, const int* in_sizes, int n_in,
                              void* d_out, int out_size, void* d_ws, size_t ws_size,
                              hipStream_t stream) {
    const float* z   = (const float*)d_in[0];
    const float* emb = (const float*)d_in[1];

    float* out      = (float*)d_out;
    float* out_zq   = out;               // 131072
    float* out_loss = out + 131072;      // 1
    float* out_idx  = out + 131073;      // 16384

    // ws layout (~4.1 MB; R2 proved ws >= 8.4 MB):
    char* w = (char*)d_ws;
    double*             acc   = (double*)w;
    unsigned*           done  = (unsigned*)(w + 8);
    unsigned*           gcnt  = (unsigned*)(w + 12);     w += 64;
    unsigned long long* key   = (unsigned long long*)w;  w += (size_t)N_ROW * 8;
    float*              Zn    = (float*)w;               w += (size_t)N_ROW * 4;
    float*              thr   = (float*)w;               w += (size_t)N_ROW * 4;
    unsigned short*     pz    = (unsigned short*)w;      w += (size_t)N_ROW * 32;
    unsigned short*     pe_hi = (unsigned short*)w;      w += (size_t)N_E * 16;
    float*              maxs  = (float*)w;               w += (size_t)N_ROW * NSPL * 4;
    unsigned*           pairs = (unsigned*)w;            w += (size_t)PCAP * 4;

    vq_prep <<<dim3(128), dim3(256), 0, stream>>>(z, emb, pz, pe_hi, Zn, key, acc, done, gcnt);
    vq_maxk <<<dim3((N_ROW / 256) * NSPL), dim3(256), 0, stream>>>(pe_hi, pz, maxs);
    vq_thr  <<<dim3(N_ROW / 256), dim3(256), 0, stream>>>(maxs, Zn, thr);
    vq_coll <<<dim3((N_ROW / 256) * NSPL), dim3(256), 0, stream>>>(pe_hi, pz, thr, pairs, gcnt);
    vq_fin2 <<<dim3(256), dim3(256), 0, stream>>>(z, emb, pairs, gcnt, Zn, key);
    vq_fin  <<<dim3(FIN_BLOCKS), dim3(256), 0, stream>>>(z, emb, key, gcnt, Zn, out_zq, out_idx, acc, done, out_loss);
}

// Round 13
// 76.482 us; speedup vs baseline: 7.6358x; 3.9838x over previous
//
#include <hip/hip_runtime.h>

// VQ-VAE VectorQuantizer2: z [4,8,64,64] f32, emb [16384,8] f32
// outputs: z_q [4,8,64,64] f32 | loss [1] f32 | idx [16384] written as f32
//
// R13 architecture (R10-proven coll chassis + R12's hi-only filter; both
// measured poisons removed):
//  prep: z bf16 hi/lo split + Zn + e bf16 HI split + key init
//  maxk: per-(row,split) max of dot~ = z . e_hi   [A=[z_hi,z_lo,z_hi,z_lo],
//        B octets [e_hi,0,0,e_hi] -> MFMA = (z_hi+z_lo).e_hi = z.e_hi exactly]
//  thr : thr[row] = max_s - W,  W = 1.5e-7*Zn + 6.8e-7*sqrt(Zn) + 2e-7
//        >= q/2 (d-ulp incl binade) + 2*delta' (R12-proven superset)
//  coll: re-sweep; leaf hit (rare) -> EXACT reference f32 chain (z from LDS)
//        -> PER-ROW fire-and-forget atomicMin(key[row], monotone(dd)<<32|k)
//        == lexicographic (dd,k) min == first-index argmin.
//        [R12's single gcnt atomicAdd serialized ALL hits through one L2
//         line with a return dependency -> 249us of stall. Distributed
//         non-returning atomics remove both.]
//  fin : gather winner, write z_q/idx, reduce loss (winner guaranteed:
//        each row's max cell hits its own threshold).

typedef short bf16x8 __attribute__((ext_vector_type(8)));
typedef float f32x4  __attribute__((ext_vector_type(4)));
typedef float f32x2  __attribute__((ext_vector_type(2)));

#define N_ROW 16384
#define N_E   16384
#define NSPL  32
#define SPLIT (N_E / NSPL)     // 512 codes per split
#define TILES (SPLIT / 16)     // 32
#define FIN_BLOCKS (N_ROW / 256)

static __device__ __forceinline__ unsigned short bf16_rne(float x) {
    unsigned u = __float_as_uint(x);
    unsigned r = (u >> 16) & 1u;
    return (unsigned short)((u + 0x7FFFu + r) >> 16);
}

// ---------------- prep: one-time conversions + init ----------------
__global__ __launch_bounds__(256) void vq_prep(const float* __restrict__ z,
                                               const float* __restrict__ emb,
                                               unsigned short* __restrict__ pz,
                                               unsigned short* __restrict__ pe_hi,
                                               float* __restrict__ Zn_arr,
                                               unsigned long long* __restrict__ key,
                                               double* __restrict__ acc,
                                               unsigned* __restrict__ done) {
    const int t = blockIdx.x * 256 + threadIdx.x;       // 0..32767
    if (t < N_ROW) {
        const int b = t >> 12, hw = t & 4095;
        const float* zp = z + (size_t)b * 32768 + hw;
        float v[8];
#pragma unroll
        for (int c = 0; c < 8; ++c) v[c] = zp[c * 4096];
        float Zn;
        {   // sequential f32 sum of squares, NO fma contraction (numerics contract)
#pragma clang fp contract(off)
            Zn = v[0] * v[0];
#pragma unroll
            for (int c = 1; c < 8; ++c) { float q = v[c] * v[c]; Zn = Zn + q; }
        }
        unsigned hb[8], lb[8];
#pragma unroll
        for (int c = 0; c < 8; ++c) {
            hb[c] = bf16_rne(v[c]);
            float hf = __uint_as_float(hb[c] << 16);
            lb[c] = bf16_rne(v[c] - hf);                // residual Sterbenz-exact
        }
        uint4 uh, ul;
        uh.x = hb[0] | (hb[1] << 16); uh.y = hb[2] | (hb[3] << 16);
        uh.z = hb[4] | (hb[5] << 16); uh.w = hb[6] | (hb[7] << 16);
        ul.x = lb[0] | (lb[1] << 16); ul.y = lb[2] | (lb[3] << 16);
        ul.z = lb[4] | (lb[5] << 16); ul.w = lb[6] | (lb[7] << 16);
        ((uint4*)pz)[(size_t)t * 2]     = uh;           // [hi octet | lo octet]
        ((uint4*)pz)[(size_t)t * 2 + 1] = ul;
        Zn_arr[t] = Zn;
        key[t] = ~0ull;
        if (t == 0) { *acc = 0.0; *done = 0u; }
    } else {
        const int k = t - N_ROW;                        // code index: HI part only
        const float* e = emb + (size_t)k * 8;
        unsigned hb[8];
#pragma unroll
        for (int c = 0; c < 8; ++c) hb[c] = bf16_rne(e[c]);
        uint4 uh;
        uh.x = hb[0] | (hb[1] << 16); uh.y = hb[2] | (hb[3] << 16);
        uh.z = hb[4] | (hb[5] << 16); uh.w = hb[6] | (hb[7] << 16);
        ((uint4*)pe_hi)[k] = uh;
    }
}

// ---------------- pass 1: per-(row,split) max of dot~, transposed store ----
__global__ __launch_bounds__(256, 4) void vq_maxk(const unsigned short* __restrict__ pe_hi,
                                                  const unsigned short* __restrict__ pz,
                                                  float* __restrict__ maxs) {
    __shared__ __align__(16) unsigned short se_hi[SPLIT * 8];   // 8 KB
    const int tid = threadIdx.x, wid = tid >> 6, lane = tid & 63;
    const int rowbase = (int)(blockIdx.x >> 5) * 256;
    const int split = blockIdx.x & 31;
    const int col = lane & 15, g = lane >> 4;
    const bool mid = (g == 1 || g == 2);                // B octets [hi,0,0,hi]

    bf16x8 afrag[4];                                    // A octets [hi,lo,hi,lo] -> (g&1)
#pragma unroll
    for (int a = 0; a < 4; ++a)
        afrag[a] = *(const bf16x8*)(pz + (size_t)(rowbase + wid * 64 + a * 16 + col) * 16 + (g & 1) * 8);

    {   // stage 512 codes x 16 B (pure copies)
        const uint4* gh = (const uint4*)(pe_hi + (size_t)split * SPLIT * 8);
        ((uint4*)se_hi)[tid]       = gh[tid];
        ((uint4*)se_hi)[tid + 256] = gh[tid + 256];
    }
    __syncthreads();

    const f32x4 zero4 = {0.f, 0.f, 0.f, 0.f};
    const bf16x8 zfrag = {0, 0, 0, 0, 0, 0, 0, 0};
    f32x2 rmax2[8];
#pragma unroll
    for (int i = 0; i < 8; ++i) rmax2[i] = (f32x2){-3.4e38f, -3.4e38f};

#pragma unroll 2
    for (int t = 0; t < TILES; ++t) {
        const bf16x8 bfrag = mid ? zfrag
                                 : *(const bf16x8*)(se_hi + (size_t)(t * 16 + col) * 8);
        f32x4 cc[4];
        cc[0] = __builtin_amdgcn_mfma_f32_16x16x32_bf16(afrag[0], bfrag, zero4, 0, 0, 0);
        cc[1] = __builtin_amdgcn_mfma_f32_16x16x32_bf16(afrag[1], bfrag, zero4, 0, 0, 0);
        cc[2] = __builtin_amdgcn_mfma_f32_16x16x32_bf16(afrag[2], bfrag, zero4, 0, 0, 0);
        cc[3] = __builtin_amdgcn_mfma_f32_16x16x32_bf16(afrag[3], bfrag, zero4, 0, 0, 0);
#pragma unroll
        for (int a = 0; a < 4; ++a) {                   // v_pk_max_f32
            f32x2 lo2 = __builtin_shufflevector(cc[a], cc[a], 0, 1);
            f32x2 hi2 = __builtin_shufflevector(cc[a], cc[a], 2, 3);
            rmax2[a * 2]     = __builtin_elementwise_max(rmax2[a * 2], lo2);
            rmax2[a * 2 + 1] = __builtin_elementwise_max(rmax2[a * 2 + 1], hi2);
        }
    }
#pragma unroll
    for (int a = 0; a < 4; ++a)
#pragma unroll
        for (int r = 0; r < 4; ++r) {
            float m = rmax2[a * 2 + (r >> 1)][r & 1];
            m = fmaxf(m, __shfl_xor(m, 1));
            m = fmaxf(m, __shfl_xor(m, 2));
            m = fmaxf(m, __shfl_xor(m, 4));
            m = fmaxf(m, __shfl_xor(m, 8));
            if (col == 0)   // TRANSPOSED: [split][row]
                maxs[(size_t)split * N_ROW + (rowbase + wid * 64 + a * 16 + g * 4 + r)] = m;
        }
}

// ---------------- tiny: global threshold per row ----------------
__global__ __launch_bounds__(256) void vq_thr(const float* __restrict__ maxs,
                                              const float* __restrict__ Zn_arr,
                                              float* __restrict__ thr) {
    const int row = blockIdx.x * 256 + threadIdx.x;
    float m = -3.4e38f;
#pragma unroll
    for (int s = 0; s < NSPL; ++s) m = fmaxf(m, maxs[(size_t)s * N_ROW + row]);
    const float Zn = Zn_arr[row];
    // W >= q/2 (ulp of d, binade-crossing) + 2*delta' (R12-proven)
    const float W = __builtin_fmaf(Zn, 1.5e-7f, __builtin_fmaf(__builtin_sqrtf(Zn), 6.8e-7f, 2e-7f));
    thr[row] = m - W;
}

// ---------------- pass 2: sweep + inline exact compare, per-row atomicMin ----
__global__ __launch_bounds__(256, 4) void vq_coll(const float* __restrict__ z,
                                                  const float* __restrict__ emb,
                                                  const unsigned short* __restrict__ pe_hi,
                                                  const unsigned short* __restrict__ pz,
                                                  const float* __restrict__ Zn_arr,
                                                  const float* __restrict__ thr_arr,
                                                  unsigned long long* __restrict__ key) {
    __shared__ __align__(16) unsigned short se_hi[SPLIT * 8];   // 8 KB
    __shared__ float se_z[8 * 256];                             // 8 KB TRANSPOSED [c][tid]
    __shared__ float sZn[256], sthr[256];                       // 2 KB
    const int tid = threadIdx.x, wid = tid >> 6, lane = tid & 63;
    const int rowbase = (int)(blockIdx.x >> 5) * 256;
    const int split = blockIdx.x & 31;
    const int col = lane & 15, g = lane >> 4;
    const bool mid = (g == 1 || g == 2);

    bf16x8 afrag[4];
#pragma unroll
    for (int a = 0; a < 4; ++a)
        afrag[a] = *(const bf16x8*)(pz + (size_t)(rowbase + wid * 64 + a * 16 + col) * 16 + (g & 1) * 8);

    {   // stage codes (copies) + exact z rows (transposed: conflict-free) + Zn/thr
        const uint4* gh = (const uint4*)(pe_hi + (size_t)split * SPLIT * 8);
        ((uint4*)se_hi)[tid]       = gh[tid];
        ((uint4*)se_hi)[tid + 256] = gh[tid + 256];
        const int row = rowbase + tid;
        const int b = row >> 12, hw = row & 4095;
#pragma unroll
        for (int c = 0; c < 8; ++c)                     // coalesced global, stride-1 LDS
            se_z[c * 256 + tid] = z[(size_t)b * 32768 + (size_t)c * 4096 + hw];
        sZn[tid]  = Zn_arr[row];
        sthr[tid] = thr_arr[row];
    }
    __syncthreads();

    f32x2 thr2[4][2];
#pragma unroll
    for (int a = 0; a < 4; ++a) {
        const int lr = wid * 64 + a * 16 + g * 4;
        thr2[a][0] = (f32x2){sthr[lr],     sthr[lr + 1]};
        thr2[a][1] = (f32x2){sthr[lr + 2], sthr[lr + 3]};
    }

    const f32x4 zero4 = {0.f, 0.f, 0.f, 0.f};
    const bf16x8 zfrag = {0, 0, 0, 0, 0, 0, 0, 0};
#pragma unroll 2
    for (int t = 0; t < TILES; ++t) {
        const bf16x8 bfrag = mid ? zfrag
                                 : *(const bf16x8*)(se_hi + (size_t)(t * 16 + col) * 8);
        f32x4 cc[4];
        cc[0] = __builtin_amdgcn_mfma_f32_16x16x32_bf16(afrag[0], bfrag, zero4, 0, 0, 0);
        cc[1] = __builtin_amdgcn_mfma_f32_16x16x32_bf16(afrag[1], bfrag, zero4, 0, 0, 0);
        cc[2] = __builtin_amdgcn_mfma_f32_16x16x32_bf16(afrag[2], bfrag, zero4, 0, 0, 0);
        cc[3] = __builtin_amdgcn_mfma_f32_16x16x32_bf16(afrag[3], bfrag, zero4, 0, 0, 0);

        f32x2 d[4][2], mx;
#pragma unroll
        for (int a = 0; a < 4; ++a) {
            f32x2 lo2 = __builtin_shufflevector(cc[a], cc[a], 0, 1);
            f32x2 hi2 = __builtin_shufflevector(cc[a], cc[a], 2, 3);
            d[a][0] = lo2 - thr2[a][0];
            d[a][1] = hi2 - thr2[a][1];
            f32x2 m2 = __builtin_elementwise_max(d[a][0], d[a][1]);
            mx = (a == 0) ? m2 : __builtin_elementwise_max(mx, m2);
        }
        if (__any(fmaxf(mx.x, mx.y) >= 0.f)) {
            const int kcode = split * SPLIT + t * 16 + col;
#pragma unroll
            for (int a = 0; a < 4; ++a)
#pragma unroll
                for (int r = 0; r < 4; ++r) {
                    const float dv = d[a][r >> 1][r & 1];
                    if (__any(dv >= 0.f)) {
                        if (dv >= 0.f) {                // leaf divergence only (rare)
                            const int lrow = wid * 64 + a * 16 + g * 4 + r;
                            const float* e = emb + (size_t)kcode * 8;
                            // EXACT chain (identical ops to reference); z via LDS
                            // (16 col-lanes share lrow -> broadcast reads)
                            float dot = se_z[lrow] * e[0];
#pragma unroll
                            for (int c = 1; c < 8; ++c)
                                dot = __builtin_fmaf(se_z[c * 256 + lrow], e[c], dot);
                            const float dd = __builtin_fmaf(-2.f, dot, sZn[lrow]);
                            unsigned u = __float_as_uint(dd);
                            unsigned mm = (u & 0x80000000u) ? ~u : (u | 0x80000000u);
                            const unsigned long long kk =
                                ((unsigned long long)mm << 32) | (unsigned)kcode;
                            atomicMin(&key[(size_t)(rowbase + lrow)], kk);  // fire-and-forget
                        }
                    }
                }
        }
    }
}

// ---------------- finalize: gather winner, outputs + loss ----------------
__global__ __launch_bounds__(256) void vq_fin(const float* __restrict__ z,
                                              const float* __restrict__ emb,
                                              const unsigned long long* __restrict__ key,
                                              float* __restrict__ out_zq,
                                              float* __restrict__ out_idx,
                                              double* __restrict__ acc,
                                              unsigned* __restrict__ done,
                                              float* __restrict__ out_loss) {
    __shared__ float red[4];
    const int row = blockIdx.x * 256 + threadIdx.x;
    const int b = row >> 12, hw = row & 4095;
    const int kstar = (int)(unsigned)(key[row] & 0xFFFFFFFFull);
    out_idx[row] = (float)kstar;
    const float* e = emb + (size_t)kstar * 8;
    float s = 0.f;
#pragma unroll
    for (int c = 0; c < 8; ++c) {
        const size_t zoff = (size_t)b * 32768 + (size_t)c * 4096 + hw;
        const float ev = e[c];
        const float df = ev - z[zoff];
        out_zq[zoff] = ev;
        s = __builtin_fmaf(df, df, s);
    }
#pragma unroll
    for (int off = 32; off > 0; off >>= 1) s += __shfl_down(s, off, 64);
    if ((threadIdx.x & 63) == 0) red[threadIdx.x >> 6] = s;
    __syncthreads();
    if (threadIdx.x == 0) {
        double t = (double)red[0] + (double)red[1] + (double)red[2] + (double)red[3];
        atomicAdd(acc, t);
        __threadfence();
        unsigned old = atomicAdd(done, 1u);
        if (old == FIN_BLOCKS - 1) {
            double total = atomicAdd(acc, 0.0);
            float mf = (float)(total / (double)(N_ROW * 8));
            out_loss[0] = mf + 0.25f * mf;   // fwd values of the two terms are equal
        }
    }
}

extern "C" void kernel_launch(void* const* d_in, const int* in_sizes, int n_in,
                              void* d_out, int out_size, void* d_ws, size_t ws_size,
                              hipStream_t stream) {
    const float* z   = (const float*)d_in[0];
    const float* emb = (const float*)d_in[1];

    float* out      = (float*)d_out;
    float* out_zq   = out;               // 131072
    float* out_loss = out + 131072;      // 1
    float* out_idx  = out + 131073;      // 16384

    // ws layout (~3.3 MB; R2 proved ws >= 8.4 MB):
    char* w = (char*)d_ws;
    double*             acc   = (double*)w;
    unsigned*           done  = (unsigned*)(w + 8);      w += 64;
    unsigned long long* key   = (unsigned long long*)w;  w += (size_t)N_ROW * 8;
    float*              Zn    = (float*)w;               w += (size_t)N_ROW * 4;
    float*              thr   = (float*)w;               w += (size_t)N_ROW * 4;
    unsigned short*     pz    = (unsigned short*)w;      w += (size_t)N_ROW * 32;
    unsigned short*     pe_hi = (unsigned short*)w;      w += (size_t)N_E * 16;
    float*              maxs  = (float*)w;               w += (size_t)N_ROW * NSPL * 4;

    vq_prep <<<dim3(128), dim3(256), 0, stream>>>(z, emb, pz, pe_hi, Zn, key, acc, done);
    vq_maxk <<<dim3((N_ROW / 256) * NSPL), dim3(256), 0, stream>>>(pe_hi, pz, maxs);
    vq_thr  <<<dim3(N_ROW / 256), dim3(256), 0, stream>>>(maxs, Zn, thr);
    vq_coll <<<dim3((N_ROW / 256) * NSPL), dim3(256), 0, stream>>>(z, emb, pe_hi, pz, Zn, thr, key);
    vq_fin  <<<dim3(FIN_BLOCKS), dim3(256), 0, stream>>>(z, emb, key, out_zq, out_idx, acc, done, out_loss);
}

// Round 14
// 60.149 us; speedup vs baseline: 9.7093x; 1.2715x over previous
//
#include <hip/hip_runtime.h>

// VQ-VAE VectorQuantizer2: z [4,8,64,64] f32, emb [16384,8] f32
// outputs: z_q [4,8,64,64] f32 | loss [1] f32 | idx [16384] written as f32
//
// R14: R13 architecture with the sweeps moved to mfma_f32_32x32x16_bf16.
//  - K=16 = [z_hi octet | z_lo octet] x [e_hi | e_hi] -> (z_hi+z_lo).e_hi
//    = z.e_hi EXACTLY (bf16 products exact in f32); same quasi-dot and
//    R12-proven window W = 1.5e-7*Zn + 6.8e-7*sqrt(Zn) + 2e-7.
//  - One MFMA = 1024 cells (4x the 16x16x32), no zero-octet masking,
//    per-cell VALU (max/detect) halves -> attacks R13's measured
//    ~113 VALU-cyc/tile overhead (maxk was 39us, the session bottleneck).
//  - C/D layout (m74/m101-verified): col=lane&31, row=(reg&3)+8*(reg>>2)+4*(lane>>5).
//    A: row=lane&31, k-octet=lane>>5 (same contiguous-octet family verified
//    for 16x16x32 in R6-R13). B octet-symmetric -> A octet order irrelevant.
//  - coll leaf: EXACT reference f32 chain + per-row fire-and-forget
//    atomicMin(key, monotone(dd)<<32|k) == first-index argmin (R13-proven).

typedef short bf16x8  __attribute__((ext_vector_type(8)));
typedef float f32x16  __attribute__((ext_vector_type(16)));
typedef float f32x2   __attribute__((ext_vector_type(2)));

#define N_ROW 16384
#define N_E   16384
#define NSPL  32
#define SPLIT (N_E / NSPL)     // 512 codes per split
#define ITER  (SPLIT / 32)     // 16 iterations of 32 codes
#define FIN_BLOCKS (N_ROW / 256)

static __device__ __forceinline__ unsigned short bf16_rne(float x) {
    unsigned u = __float_as_uint(x);
    unsigned r = (u >> 16) & 1u;
    return (unsigned short)((u + 0x7FFFu + r) >> 16);
}

// ---------------- prep: one-time conversions + init (R13-proven) ------------
__global__ __launch_bounds__(256) void vq_prep(const float* __restrict__ z,
                                               const float* __restrict__ emb,
                                               unsigned short* __restrict__ pz,
                                               unsigned short* __restrict__ pe_hi,
                                               float* __restrict__ Zn_arr,
                                               unsigned long long* __restrict__ key,
                                               double* __restrict__ acc,
                                               unsigned* __restrict__ done) {
    const int t = blockIdx.x * 256 + threadIdx.x;       // 0..32767
    if (t < N_ROW) {
        const int b = t >> 12, hw = t & 4095;
        const float* zp = z + (size_t)b * 32768 + hw;
        float v[8];
#pragma unroll
        for (int c = 0; c < 8; ++c) v[c] = zp[c * 4096];
        float Zn;
        {   // sequential f32 sum of squares, NO fma contraction (numerics contract)
#pragma clang fp contract(off)
            Zn = v[0] * v[0];
#pragma unroll
            for (int c = 1; c < 8; ++c) { float q = v[c] * v[c]; Zn = Zn + q; }
        }
        unsigned hb[8], lb[8];
#pragma unroll
        for (int c = 0; c < 8; ++c) {
            hb[c] = bf16_rne(v[c]);
            float hf = __uint_as_float(hb[c] << 16);
            lb[c] = bf16_rne(v[c] - hf);                // residual Sterbenz-exact
        }
        uint4 uh, ul;
        uh.x = hb[0] | (hb[1] << 16); uh.y = hb[2] | (hb[3] << 16);
        uh.z = hb[4] | (hb[5] << 16); uh.w = hb[6] | (hb[7] << 16);
        ul.x = lb[0] | (lb[1] << 16); ul.y = lb[2] | (lb[3] << 16);
        ul.z = lb[4] | (lb[5] << 16); ul.w = lb[6] | (lb[7] << 16);
        ((uint4*)pz)[(size_t)t * 2]     = uh;           // [hi octet | lo octet]
        ((uint4*)pz)[(size_t)t * 2 + 1] = ul;
        Zn_arr[t] = Zn;
        key[t] = ~0ull;
        if (t == 0) { *acc = 0.0; *done = 0u; }
    } else {
        const int k = t - N_ROW;                        // code index: HI part only
        const float* e = emb + (size_t)k * 8;
        unsigned hb[8];
#pragma unroll
        for (int c = 0; c < 8; ++c) hb[c] = bf16_rne(e[c]);
        uint4 uh;
        uh.x = hb[0] | (hb[1] << 16); uh.y = hb[2] | (hb[3] << 16);
        uh.z = hb[4] | (hb[5] << 16); uh.w = hb[6] | (hb[7] << 16);
        ((uint4*)pe_hi)[k] = uh;
    }
}

// ---------------- pass 1: per-(row,split) max of dot~ (32x32 MFMA) ----------
__global__ __launch_bounds__(256, 4) void vq_maxk(const unsigned short* __restrict__ pe_hi,
                                                  const unsigned short* __restrict__ pz,
                                                  float* __restrict__ maxs) {
    __shared__ __align__(16) unsigned short se_hi[SPLIT * 8];   // 8 KB
    const int tid = threadIdx.x, wid = tid >> 6, lane = tid & 63;
    const int rowbase = (int)(blockIdx.x >> 5) * 256;
    const int split = blockIdx.x & 31;
    const int c32 = lane & 31, hi = lane >> 5;

    // A: row = lane&31, k-octet = lane>>5 -> [z_hi | z_lo]
    bf16x8 afrag[2];
#pragma unroll
    for (int a = 0; a < 2; ++a)
        afrag[a] = *(const bf16x8*)(pz + (size_t)(rowbase + wid * 64 + a * 32 + c32) * 16 + hi * 8);

    {   // stage 512 codes x 16 B (pure copies)
        const uint4* gh = (const uint4*)(pe_hi + (size_t)split * SPLIT * 8);
        ((uint4*)se_hi)[tid]       = gh[tid];
        ((uint4*)se_hi)[tid + 256] = gh[tid + 256];
    }
    __syncthreads();

    const f32x16 zero16 = {0.f,0.f,0.f,0.f,0.f,0.f,0.f,0.f,0.f,0.f,0.f,0.f,0.f,0.f,0.f,0.f};
    f32x2 rmax2[2][8];
#pragma unroll
    for (int a = 0; a < 2; ++a)
#pragma unroll
        for (int j = 0; j < 8; ++j) rmax2[a][j] = (f32x2){-3.4e38f, -3.4e38f};

#pragma unroll 2
    for (int t = 0; t < ITER; ++t) {
        // B: col = lane&31, both k-octets read e_hi (same addr both halves: broadcast)
        const bf16x8 bfrag = *(const bf16x8*)(se_hi + (size_t)(t * 32 + c32) * 8);
        f32x16 cc0 = __builtin_amdgcn_mfma_f32_32x32x16_bf16(afrag[0], bfrag, zero16, 0, 0, 0);
        f32x16 cc1 = __builtin_amdgcn_mfma_f32_32x32x16_bf16(afrag[1], bfrag, zero16, 0, 0, 0);
#pragma unroll
        for (int j = 0; j < 8; ++j) {                   // v_pk_max_f32
            rmax2[0][j] = __builtin_elementwise_max(rmax2[0][j], (f32x2){cc0[2*j], cc0[2*j+1]});
            rmax2[1][j] = __builtin_elementwise_max(rmax2[1][j], (f32x2){cc1[2*j], cc1[2*j+1]});
        }
    }
    // cross-lane reduce over the 32 code-columns, store maxs[split][row]
#pragma unroll
    for (int a = 0; a < 2; ++a)
#pragma unroll
        for (int reg = 0; reg < 16; ++reg) {
            float m = rmax2[a][reg >> 1][reg & 1];
            m = fmaxf(m, __shfl_xor(m, 1));
            m = fmaxf(m, __shfl_xor(m, 2));
            m = fmaxf(m, __shfl_xor(m, 4));
            m = fmaxf(m, __shfl_xor(m, 8));
            m = fmaxf(m, __shfl_xor(m, 16));
            if (c32 == 0) {
                const int row = rowbase + wid * 64 + a * 32 + (reg & 3) + 8 * (reg >> 2) + 4 * hi;
                maxs[(size_t)split * N_ROW + row] = m;
            }
        }
}

// ---------------- tiny: global threshold per row (R13-proven) ----------------
__global__ __launch_bounds__(256) void vq_thr(const float* __restrict__ maxs,
                                              const float* __restrict__ Zn_arr,
                                              float* __restrict__ thr) {
    const int row = blockIdx.x * 256 + threadIdx.x;
    float m = -3.4e38f;
#pragma unroll
    for (int s = 0; s < NSPL; ++s) m = fmaxf(m, maxs[(size_t)s * N_ROW + row]);
    const float Zn = Zn_arr[row];
    // W >= q/2 (ulp of d, binade-crossing) + 2*delta' (R12-proven)
    const float W = __builtin_fmaf(Zn, 1.5e-7f, __builtin_fmaf(__builtin_sqrtf(Zn), 6.8e-7f, 2e-7f));
    thr[row] = m - W;
}

// ---------------- pass 2: sweep + inline exact compare, per-row atomicMin ----
__global__ __launch_bounds__(256, 4) void vq_coll(const float* __restrict__ z,
                                                  const float* __restrict__ emb,
                                                  const unsigned short* __restrict__ pe_hi,
                                                  const unsigned short* __restrict__ pz,
                                                  const float* __restrict__ Zn_arr,
                                                  const float* __restrict__ thr_arr,
                                                  unsigned long long* __restrict__ key) {
    __shared__ __align__(16) unsigned short se_hi[SPLIT * 8];   // 8 KB
    __shared__ float se_z[8 * 256];                             // 8 KB TRANSPOSED [c][tid]
    __shared__ float sZn[256], sthr[256];                       // 2 KB
    const int tid = threadIdx.x, wid = tid >> 6, lane = tid & 63;
    const int rowbase = (int)(blockIdx.x >> 5) * 256;
    const int split = blockIdx.x & 31;
    const int c32 = lane & 31, hi = lane >> 5;

    bf16x8 afrag[2];
#pragma unroll
    for (int a = 0; a < 2; ++a)
        afrag[a] = *(const bf16x8*)(pz + (size_t)(rowbase + wid * 64 + a * 32 + c32) * 16 + hi * 8);

    {   // stage codes (copies) + exact z rows (transposed: conflict-free) + Zn/thr
        const uint4* gh = (const uint4*)(pe_hi + (size_t)split * SPLIT * 8);
        ((uint4*)se_hi)[tid]       = gh[tid];
        ((uint4*)se_hi)[tid + 256] = gh[tid + 256];
        const int row = rowbase + tid;
        const int b = row >> 12, hw = row & 4095;
#pragma unroll
        for (int c = 0; c < 8; ++c)                     // coalesced global, stride-1 LDS
            se_z[c * 256 + tid] = z[(size_t)b * 32768 + (size_t)c * 4096 + hw];
        sZn[tid]  = Zn_arr[row];
        sthr[tid] = thr_arr[row];
    }
    __syncthreads();

    // per-reg-pair thresholds: reg pair (2j,2j+1) -> rows base+(2j&3)+8*(j>>1) +{0,1}
    f32x2 thr2[2][8];
#pragma unroll
    for (int a = 0; a < 2; ++a) {
        const int base = wid * 64 + a * 32 + 4 * hi;
#pragma unroll
        for (int j = 0; j < 8; ++j) {
            const int r0 = base + ((2 * j) & 3) + 8 * (j >> 1);
            thr2[a][j] = (f32x2){sthr[r0], sthr[r0 + 1]};
        }
    }

    const f32x16 zero16 = {0.f,0.f,0.f,0.f,0.f,0.f,0.f,0.f,0.f,0.f,0.f,0.f,0.f,0.f,0.f,0.f};
#pragma unroll 2
    for (int t = 0; t < ITER; ++t) {
        const bf16x8 bfrag = *(const bf16x8*)(se_hi + (size_t)(t * 32 + c32) * 8);
        f32x16 cc0 = __builtin_amdgcn_mfma_f32_32x32x16_bf16(afrag[0], bfrag, zero16, 0, 0, 0);
        f32x16 cc1 = __builtin_amdgcn_mfma_f32_32x32x16_bf16(afrag[1], bfrag, zero16, 0, 0, 0);

        f32x2 dd[2][8];
#pragma unroll
        for (int j = 0; j < 8; ++j) {
            dd[0][j] = (f32x2){cc0[2*j], cc0[2*j+1]} - thr2[0][j];
            dd[1][j] = (f32x2){cc1[2*j], cc1[2*j+1]} - thr2[1][j];
        }
        f32x2 mx = dd[0][0];
#pragma unroll
        for (int j = 1; j < 8; ++j) mx = __builtin_elementwise_max(mx, dd[0][j]);
#pragma unroll
        for (int j = 0; j < 8; ++j) mx = __builtin_elementwise_max(mx, dd[1][j]);

        if (__any(fmaxf(mx.x, mx.y) >= 0.f)) {
            const int kcode = split * SPLIT + t * 32 + c32;
#pragma unroll
            for (int a = 0; a < 2; ++a) {
                f32x2 am = dd[a][0];
#pragma unroll
                for (int j = 1; j < 8; ++j) am = __builtin_elementwise_max(am, dd[a][j]);
                if (__any(fmaxf(am.x, am.y) >= 0.f)) {
#pragma unroll
                    for (int j = 0; j < 8; ++j)
#pragma unroll
                        for (int h = 0; h < 2; ++h) {
                            const float dv = dd[a][j][h];
                            if (__any(dv >= 0.f)) {
                                if (dv >= 0.f) {        // leaf divergence only (rare)
                                    const int reg = 2 * j + h;
                                    const int lrow = wid * 64 + a * 32 + (reg & 3) + 8 * (reg >> 2) + 4 * hi;
                                    const float* e = emb + (size_t)kcode * 8;
                                    // EXACT chain (identical ops to reference); z via
                                    // LDS broadcast (32 col-lanes share lrow)
                                    float dot = se_z[lrow] * e[0];
#pragma unroll
                                    for (int c = 1; c < 8; ++c)
                                        dot = __builtin_fmaf(se_z[c * 256 + lrow], e[c], dot);
                                    const float ddv = __builtin_fmaf(-2.f, dot, sZn[lrow]);
                                    unsigned u = __float_as_uint(ddv);
                                    unsigned mm = (u & 0x80000000u) ? ~u : (u | 0x80000000u);
                                    const unsigned long long kk =
                                        ((unsigned long long)mm << 32) | (unsigned)kcode;
                                    atomicMin(&key[(size_t)(rowbase + lrow)], kk);  // fire-and-forget
                                }
                            }
                        }
                }
            }
        }
    }
}

// ---------------- finalize: gather winner, outputs + loss (R13-proven) ------
__global__ __launch_bounds__(256) void vq_fin(const float* __restrict__ z,
                                              const float* __restrict__ emb,
                                              const unsigned long long* __restrict__ key,
                                              float* __restrict__ out_zq,
                                              float* __restrict__ out_idx,
                                              double* __restrict__ acc,
                                              unsigned* __restrict__ done,
                                              float* __restrict__ out_loss) {
    __shared__ float red[4];
    const int row = blockIdx.x * 256 + threadIdx.x;
    const int b = row >> 12, hw = row & 4095;
    const int kstar = (int)(unsigned)(key[row] & 0xFFFFFFFFull);
    out_idx[row] = (float)kstar;
    const float* e = emb + (size_t)kstar * 8;
    float s = 0.f;
#pragma unroll
    for (int c = 0; c < 8; ++c) {
        const size_t zoff = (size_t)b * 32768 + (size_t)c * 4096 + hw;
        const float ev = e[c];
        const float df = ev - z[zoff];
        out_zq[zoff] = ev;
        s = __builtin_fmaf(df, df, s);
    }
#pragma unroll
    for (int off = 32; off > 0; off >>= 1) s += __shfl_down(s, off, 64);
    if ((threadIdx.x & 63) == 0) red[threadIdx.x >> 6] = s;
    __syncthreads();
    if (threadIdx.x == 0) {
        double t = (double)red[0] + (double)red[1] + (double)red[2] + (double)red[3];
        atomicAdd(acc, t);
        __threadfence();
        unsigned old = atomicAdd(done, 1u);
        if (old == FIN_BLOCKS - 1) {
            double total = atomicAdd(acc, 0.0);
            float mf = (float)(total / (double)(N_ROW * 8));
            out_loss[0] = mf + 0.25f * mf;   // fwd values of the two terms are equal
        }
    }
}

extern "C" void kernel_launch(void* const* d_in, const int* in_sizes, int n_in,
                              void* d_out, int out_size, void* d_ws, size_t ws_size,
                              hipStream_t stream) {
    const float* z   = (const float*)d_in[0];
    const float* emb = (const float*)d_in[1];

    float* out      = (float*)d_out;
    float* out_zq   = out;               // 131072
    float* out_loss = out + 131072;      // 1
    float* out_idx  = out + 131073;      // 16384

    // ws layout (~3.3 MB; R2 proved ws >= 8.4 MB):
    char* w = (char*)d_ws;
    double*             acc   = (double*)w;
    unsigned*           done  = (unsigned*)(w + 8);      w += 64;
    unsigned long long* key   = (unsigned long long*)w;  w += (size_t)N_ROW * 8;
    float*              Zn    = (float*)w;               w += (size_t)N_ROW * 4;
    float*              thr   = (float*)w;               w += (size_t)N_ROW * 4;
    unsigned short*     pz    = (unsigned short*)w;      w += (size_t)N_ROW * 32;
    unsigned short*     pe_hi = (unsigned short*)w;      w += (size_t)N_E * 16;
    float*              maxs  = (float*)w;               w += (size_t)N_ROW * NSPL * 4;

    vq_prep <<<dim3(128), dim3(256), 0, stream>>>(z, emb, pz, pe_hi, Zn, key, acc, done);
    vq_maxk <<<dim3((N_ROW / 256) * NSPL), dim3(256), 0, stream>>>(pe_hi, pz, maxs);
    vq_thr  <<<dim3(N_ROW / 256), dim3(256), 0, stream>>>(maxs, Zn, thr);
    vq_coll <<<dim3((N_ROW / 256) * NSPL), dim3(256), 0, stream>>>(z, emb, pe_hi, pz, Zn, thr, key);
    vq_fin  <<<dim3(FIN_BLOCKS), dim3(256), 0, stream>>>(z, emb, key, out_zq, out_idx, acc, done, out_loss);
}